// Round 14
// baseline (3413.549 us; speedup 1.0000x reference)
//
#include <hip/hip_runtime.h>

// ---------------- problem constants ----------------
#define TPB   256
#define NWG   512
#define SEQL  200
#define BATCH 64
#define EDIM  300
#define HDIM  512
#define ODIM  5

// ---------------- group decomposition ----------------
#define GROUPS 16     // independent batch groups (group = blockIdx & 15)
#define GB     4      // batch rows per group
#define UNITS  16     // h units per block

// ---------------- persist-kernel LDS layout (word offsets) ----------------
// [0..2048)     h tile [512 k][4 b]; phys = (4k ^ (((k>>5)&3)<<2)) + b
//               wave w writes+reads ONLY rows [128w,128w+128) -> wave-private
// [2048..6464)  ex[64 r][4 b][16 kh]: addr = 2048 + r*69 + b*17 + kh
// [6464..7664)  embT[300][4]; wave w's slice [320w, 320w+320) is wave-private
#define EX_OFF   2048
#define EX_RSTR  69
#define EX_BSTR  17
#define EMB_OFF  6464
#define LDS_BYTES 56320                      // 55 KiB: 2 blocks/CU fit, 3 don't

// ---------------- tagged h exchange ----------------
// htag[parity][group][2048] : ull = (tag << 32) | f32bits(value)
// value index vi = k*4 + b. Input for step s: parity s&1, tag == s.
#define HT_GROUP 2048
#define HT_PAR   (GROUPS * HT_GROUP)               // 32768 ull per parity
#define HT_BYTES (2 * HT_PAR * 8)                  // 512 KiB

__device__ __forceinline__ float fast_sigmoid(float x) {
    return 1.0f / (1.0f + __expf(-x));
}
__device__ __forceinline__ float fast_tanh(float x) {
    return 2.0f / (1.0f + __expf(-2.0f * x)) - 1.0f;
}

// ============================================================================
// Persistent LSTM, 16 groups x 32 blocks, 2 blocks/CU (r12 structure) with the
// input projection FUSED into each step (no lstm_pre, no gates stream):
// wave-local embT staging (5 gathers/lane, in-wave RAW, no barrier) + 80-VGPR
// W_ih slice -> pass A runs in the shadow of the h visibility wait.
// ============================================================================
extern "C" __global__ void __launch_bounds__(TPB, 2)
lstm_persist(const int* __restrict__ x, const float* __restrict__ emb,
             const float* __restrict__ W_ih, const float* __restrict__ W_hh,
             const float* __restrict__ b_ih, const float* __restrict__ b_hh,
             unsigned long long* __restrict__ htag) // [2][16][2048] tagged h
{
    extern __shared__ float lds[];
    const int tid = threadIdx.x;
    const int g   = blockIdx.x & 15;
    const int j   = blockIdx.x >> 4;        // 0..31
    const int rq  = tid & 15;      // rows 4rq..4rq+3 (r = gate*16+u)
    const int kh  = tid >> 4;      // k in [32kh, 32kh+32)
    const int wv  = tid >> 6;      // wave 0..3
    const int ln  = tid & 63;      // lane

    // ---- W_hh slice -> 128 VGPRs (static indexing only; rule #20) ----
    float4 w4[4][8];
#pragma unroll
    for (int p = 0; p < 4; p++) {
        const int r = 4 * rq + p;
        const size_t R = (size_t)((r >> 4) * HDIM + UNITS * j + (r & 15));
        const float* wp = W_hh + R * HDIM + 32 * kh;
#pragma unroll
        for (int kq = 0; kq < 8; kq++) w4[p][kq] = *(const float4*)(wp + 4 * kq);
    }

    // ---- W_ih slice -> 80 VGPRs: rows 4rq..4rq+3, e in [20kh, 20kh+20) ----
    float4 wih[4][5];
#pragma unroll
    for (int p = 0; p < 4; p++)
#pragma unroll
        for (int eq = 0; eq < 5; eq++)
            wih[p][eq] = make_float4(0.f, 0.f, 0.f, 0.f);
    if (kh < 15) {
#pragma unroll
        for (int p = 0; p < 4; p++) {
            const int r = 4 * rq + p;
            const size_t R = (size_t)((r >> 4) * HDIM + UNITS * j + (r & 15));
            const float* wp = W_ih + R * EDIM + 20 * kh;
#pragma unroll
            for (int eq = 0; eq < 5; eq++) wih[p][eq] = *(const float4*)(wp + 4 * eq);
        }
    }

    // cell role: tid<64 owns (u = tid>>2, b = tid&3)
    const int uu = (tid & 63) >> 2;
    const int cb = tid & 3;
    float bias4[4];
#pragma unroll
    for (int gt = 0; gt < 4; gt++) {
        int R = gt * HDIM + UNITS * j + uu;
        bias4[gt] = b_ih[R] + b_hh[R];
    }
    float c_reg = 0.0f;

    const int swz = (kh & 3) << 2;      // pass-B read swizzle

    unsigned long long* const T0 = htag + (size_t)g * HT_GROUP;            // parity 0
    unsigned long long* const T1 = htag + HT_PAR + (size_t)g * HT_GROUP;   // parity 1

    __syncthreads();

    for (int s = 0; s < SEQL; s++) {
        const unsigned long long* Tin = (s & 1) ? T1 : T0;
        unsigned long long*       Tout = (s & 1) ? T0 : T1;

        float acc[4][4];
#pragma unroll
        for (int p = 0; p < 4; p++)
#pragma unroll
            for (int b = 0; b < 4; b++) acc[p][b] = 0.f;

        // ---- (1) FUSED pass A: wave-local embT stage + 80-VGPR W_ih slice ----
        // Lane's batch column is constant (b = ln&3); wave w stages its own
        // e-slice [80w, 80w+80) -> in-wave RAW, no barrier. Runs in the shadow
        // of the producer-h visibility gap (all blocks are schedule-symmetric).
        {
            const int b = ln & 3;
            const int row = x[(GB * g + b) * SEQL + s];
            const float* ebase = emb + (size_t)row * EDIM;
            const int i1 = (wv == 3) ? (EDIM * GB) : 320 * wv + 320;
            for (int i = 320 * wv + ln; i < i1; i += 64)
                lds[EMB_OFF + i] = ebase[i >> 2];
            asm volatile("" ::: "memory");
            __builtin_amdgcn_sched_barrier(0);
            if (kh < 15) {
#pragma unroll
                for (int eq = 0; eq < 5; eq++) {
#pragma unroll
                    for (int ei = 0; ei < 4; ei++) {
                        const int e = 20 * kh + 4 * eq + ei;
                        const float4 ev = *(const float4*)&lds[EMB_OFF + 4 * e];
#pragma unroll
                        for (int p = 0; p < 4; p++) {
                            const float4 wvv = wih[p][eq];
                            const float wc = ei == 0 ? wvv.x : ei == 1 ? wvv.y
                                           : ei == 2 ? wvv.z : wvv.w;
                            acc[p][0] = fmaf(wc, ev.x, acc[p][0]);
                            acc[p][1] = fmaf(wc, ev.y, acc[p][1]);
                            acc[p][2] = fmaf(wc, ev.z, acc[p][2]);
                            acc[p][3] = fmaf(wc, ev.w, acc[p][3]);
                        }
                    }
                }
            }
        }

        // ---- (2) WAVE-LOCAL poll+stage: lane stages k = 128*wv + {0,64} + ln ----
        {
            const unsigned tag = (unsigned)s;
#pragma unroll
            for (int rr = 0; rr < 2; rr++) {
                const int k = 128 * wv + 64 * rr + ln;
                const int vi = 4 * k;
                unsigned long long d0, d1, d2, d3;
                for (;;) {
                    d0 = __hip_atomic_load(Tin + vi + 0, __ATOMIC_RELAXED, __HIP_MEMORY_SCOPE_AGENT);
                    d1 = __hip_atomic_load(Tin + vi + 1, __ATOMIC_RELAXED, __HIP_MEMORY_SCOPE_AGENT);
                    d2 = __hip_atomic_load(Tin + vi + 2, __ATOMIC_RELAXED, __HIP_MEMORY_SCOPE_AGENT);
                    d3 = __hip_atomic_load(Tin + vi + 3, __ATOMIC_RELAXED, __HIP_MEMORY_SCOPE_AGENT);
                    if ((unsigned)(d0 >> 32) == tag && (unsigned)(d1 >> 32) == tag &&
                        (unsigned)(d2 >> 32) == tag && (unsigned)(d3 >> 32) == tag)
                        break;
                    __builtin_amdgcn_s_sleep(1);
                }
                const int phys = (4 * k) ^ (((k >> 5) & 3) << 2);
                float4 hv;
                hv.x = __uint_as_float((unsigned)d0);
                hv.y = __uint_as_float((unsigned)d1);
                hv.z = __uint_as_float((unsigned)d2);
                hv.w = __uint_as_float((unsigned)d3);
                *(float4*)&lds[phys] = hv;
            }
        }
        // wave-local RAW through LDS (in-order DS pipe); stop compiler reorder
        asm volatile("" ::: "memory");
        __builtin_amdgcn_sched_barrier(0);

        // ---- (3) pass B: W_hh regs x h LDS (conflict-free reads) ----
#pragma unroll
        for (int kq = 0; kq < 8; kq++) {
#pragma unroll
            for (int ki = 0; ki < 4; ki++) {
                const int kidx = 4 * kq + ki;
                const float4 h0 = *(const float4*)&lds[128 * kh + ((4 * kidx) ^ swz)];
#pragma unroll
                for (int p = 0; p < 4; p++) {
                    const float4 wvv = w4[p][kq];
                    const float wc = ki == 0 ? wvv.x : ki == 1 ? wvv.y
                                   : ki == 2 ? wvv.z : wvv.w;
                    acc[p][0] = fmaf(wc, h0.x, acc[p][0]);
                    acc[p][1] = fmaf(wc, h0.y, acc[p][1]);
                    acc[p][2] = fmaf(wc, h0.z, acc[p][2]);
                    acc[p][3] = fmaf(wc, h0.w, acc[p][3]);
                }
            }
        }

        // ---- (4) exchange k-partials: ex[r][b][kh] ----
#pragma unroll
        for (int p = 0; p < 4; p++) {
            const int base = EX_OFF + (4 * rq + p) * EX_RSTR + kh;
#pragma unroll
            for (int b = 0; b < 4; b++)
                lds[base + b * EX_BSTR] = acc[p][b];
        }
        __syncthreads();   // B1: all ex writes visible to cell readers

        // ---- (5) cell update + tagged store (tid<64 owns (u, b)) ----
        if (tid < 64) {
            float gs[4];
#pragma unroll
            for (int gt = 0; gt < 4; gt++) {
                float sum = bias4[gt];
                const int base = EX_OFF + (gt * 16 + uu) * EX_RSTR + cb * EX_BSTR;
#pragma unroll
                for (int kk = 0; kk < 16; kk++) sum += lds[base + kk];
                gs[gt] = sum;
            }
            float iv = fast_sigmoid(gs[0]);
            float fv = fast_sigmoid(gs[1]);
            float gv = fast_tanh(gs[2]);
            float ov = fast_sigmoid(gs[3]);
            c_reg = fv * c_reg + iv * gv;
            float hv = ov * fast_tanh(c_reg);
            // vi = (16j+u)*4 + b = 64j + tid ; tag = s+1
            unsigned long long wword =
                ((unsigned long long)(unsigned)(s + 1) << 32) |
                (unsigned long long)__float_as_uint(hv);
            __hip_atomic_store(Tout + 64 * j + tid, wword,
                               __ATOMIC_RELAXED, __HIP_MEMORY_SCOPE_AGENT);
        }
        __syncthreads();   // B2: cell reads done before next step's ex writes
    }
}

// FC head + softmax. Final h: parity 0 (SEQL even); value = lo32.
extern "C" __global__ void __launch_bounds__(320)
lstm_epilogue(const unsigned long long* __restrict__ htag,
              const float* __restrict__ W_fc, const float* __restrict__ b_fc,
              float* __restrict__ out)
{
    __shared__ float sl[ODIM * BATCH];
    const int t = threadIdx.x;
    {
        int o = t / BATCH, b = t - o * BATCH;
        const unsigned long long* hb = htag + (size_t)(b >> 2) * HT_GROUP;
        const int bc = b & 3;
        float acc = b_fc[o];
        const float4* wv = (const float4*)(W_fc + o * HDIM);
#pragma unroll 8
        for (int k4 = 0; k4 < HDIM / 4; k4++) {
            float4 w = wv[k4];
            const int k0 = 4 * k4;
            acc = fmaf(__uint_as_float((unsigned)hb[(k0 + 0) * 4 + bc]), w.x, acc);
            acc = fmaf(__uint_as_float((unsigned)hb[(k0 + 1) * 4 + bc]), w.y, acc);
            acc = fmaf(__uint_as_float((unsigned)hb[(k0 + 2) * 4 + bc]), w.z, acc);
            acc = fmaf(__uint_as_float((unsigned)hb[(k0 + 3) * 4 + bc]), w.w, acc);
        }
        sl[o * BATCH + b] = acc;
    }
    __syncthreads();
    if (t < BATCH) {
        float l0 = sl[t], l1 = sl[BATCH + t], l2 = sl[2 * BATCH + t];
        float l3 = sl[3 * BATCH + t], l4 = sl[4 * BATCH + t];
        float m = fmaxf(fmaxf(fmaxf(l0, l1), fmaxf(l2, l3)), l4);
        float e0 = __expf(l0 - m), e1 = __expf(l1 - m), e2 = __expf(l2 - m);
        float e3 = __expf(l3 - m), e4 = __expf(l4 - m);
        float inv = 1.0f / (e0 + e1 + e2 + e3 + e4);
        out[t * ODIM + 0] = e0 * inv;
        out[t * ODIM + 1] = e1 * inv;
        out[t * ODIM + 2] = e2 * inv;
        out[t * ODIM + 3] = e3 * inv;
        out[t * ODIM + 4] = e4 * inv;
    }
}

extern "C" void kernel_launch(void* const* d_in, const int* in_sizes, int n_in,
                              void* d_out, int out_size, void* d_ws, size_t ws_size,
                              hipStream_t stream)
{
    const int*   x    = (const int*)d_in[0];
    const float* emb  = (const float*)d_in[1];
    const float* W_ih = (const float*)d_in[2];
    const float* W_hh = (const float*)d_in[3];
    const float* b_ih = (const float*)d_in[4];
    const float* b_hh = (const float*)d_in[5];
    const float* W_fc = (const float*)d_in[6];
    const float* b_fc = (const float*)d_in[7];
    float* out = (float*)d_out;

    unsigned long long* htag = (unsigned long long*)d_ws;
    (void)hipMemsetAsync(htag, 0, HT_BYTES, stream);   // tag 0 / h = 0 for step 0

    (void)hipFuncSetAttribute((const void*)lstm_persist,
                              hipFuncAttributeMaxDynamicSharedMemorySize, LDS_BYTES);

    lstm_persist<<<NWG, TPB, LDS_BYTES, stream>>>(x, emb, W_ih, W_hh,
                                                  b_ih, b_hh, htag);

    lstm_epilogue<<<1, 320, 0, stream>>>(htag, W_fc, b_fc, out);
}

// Round 15
// 1452.464 us; speedup vs baseline: 2.3502x; 2.3502x over previous
//
#include <hip/hip_runtime.h>

// ---------------- problem constants ----------------
#define TPB   256
#define NWG   512
#define SEQL  200
#define BATCH 64
#define EDIM  300
#define HDIM  512
#define ODIM  5
#define NROW  (4*HDIM)   // 2048 gate rows

// ---------------- group decomposition ----------------
#define GROUPS 16     // independent batch groups (group = blockIdx & 15)
#define GB     4      // batch rows per group
#define UNITS  16     // h units per block

// ---------------- persist-kernel LDS layout (word offsets) — r12 verbatim ----
#define EX_OFF   2048
#define EX_RSTR  69
#define EX_BSTR  17
#define EMB_OFF  (EX_OFF + 64*EX_RSTR)       // 6464
#define LDS_BYTES 56320                      // 55 KiB: 2 blocks/CU fit, 3 don't

// ---------------- tagged h exchange ----------------
#define HT_GROUP 2048
#define HT_PAR   (GROUPS * HT_GROUP)               // 32768 ull per parity
#define HT_BYTES (2 * HT_PAR * 8)                  // 512 KiB

// ---------------- precompute-kernel LDS ----------------
#define ESTR 308
#define PRE_LDS_BYTES (BATCH * ESTR * 4)     // 78848 B

#define GATES_FLOATS ((size_t)SEQL * NROW * BATCH)   // 104.9 MB
#define WT_FLOATS    ((size_t)EDIM * NROW)           // 614400 (2.4 MB)

__device__ __forceinline__ float fast_sigmoid(float x) {
    return 1.0f / (1.0f + __expf(-x));
}
__device__ __forceinline__ float fast_tanh(float x) {
    return 2.0f / (1.0f + __expf(-2.0f * x)) - 1.0f;
}

// ============================================================================
// W_ih transpose: WT[e][row] = W_ih[row][e].  Tiled 32x32 via LDS; both global
// access directions coalesced. grid = (2048/32) x ceil(300/32).
// ============================================================================
extern "C" __global__ void __launch_bounds__(256)
wih_transpose(const float* __restrict__ W, float* __restrict__ WT)
{
    __shared__ float t[32][33];
    const int r0 = blockIdx.x * 32;
    const int e0 = blockIdx.y * 32;
    const int le = threadIdx.x & 31;     // e-offset on read / r-offset on write
    const int lr = threadIdx.x >> 5;     // 8 per iter

    for (int rr = lr; rr < 32; rr += 8) {
        const int e = e0 + le;
        t[rr][le] = (e < EDIM) ? W[(size_t)(r0 + rr) * EDIM + e] : 0.0f;
    }
    __syncthreads();
    for (int ee = lr; ee < 32; ee += 8) {
        const int e = e0 + ee;
        if (e < EDIM) WT[(size_t)e * NROW + r0 + le] = t[le][ee];
    }
}

// ============================================================================
// Precompute: gates[s][group][row][4] = (x_s @ W_ih^T) for batch 4g..4g+3.
// If wT != null, W reads are COALESCED via W_ihT[e][row] (lanes ri stride
// 32B -> 1KB/wave-instr); else fall back to the r12 scattered-read path.
// ============================================================================
extern "C" __global__ void __launch_bounds__(256, 1)
lstm_pre(const int* __restrict__ x, const float* __restrict__ emb,
         const float* __restrict__ W_ih, const float* __restrict__ wT,
         float* __restrict__ gates)
{
    extern __shared__ float embs[];
    const int tid = threadIdx.x;
    const int s   = blockIdx.x >> 3;
    const int rb  = blockIdx.x & 7;

    for (int i = tid; i < BATCH * 75; i += 256) {
        int b = i / 75, jj = i - b * 75;
        int row = x[b * SEQL + s];
        float4 v = ((const float4*)(emb + (size_t)row * EDIM))[jj];
        *(float4*)&embs[b * ESTR + 4 * jj] = v;
    }
    __syncthreads();

    const int bi = tid >> 5;      // batch octet (groups 2bi, 2bi+1)
    const int ri = tid & 31;
    const int row0 = rb * 256 + ri * 8;

    float acc[8][8];
#pragma unroll
    for (int a = 0; a < 8; a++)
#pragma unroll
        for (int b = 0; b < 8; b++) acc[a][b] = 0.0f;

    if (wT) {
        // coalesced path: per t2, 8 x float4 of WT[e][row0..row0+8]
        for (int t2 = 0; t2 < 75; t2++) {
            float4 wA[4], wB[4], e[8];
#pragma unroll
            for (int c = 0; c < 4; c++) {
                const float* p = wT + (size_t)(4 * t2 + c) * NROW + row0;
                wA[c] = *(const float4*)p;
                wB[c] = *(const float4*)(p + 4);
            }
#pragma unroll
            for (int bb = 0; bb < 8; bb++)
                e[bb] = *(const float4*)&embs[(bi * 8 + bb) * ESTR + 4 * t2];
#pragma unroll
            for (int c = 0; c < 4; c++) {
                float wr[8];
                wr[0] = wA[c].x; wr[1] = wA[c].y; wr[2] = wA[c].z; wr[3] = wA[c].w;
                wr[4] = wB[c].x; wr[5] = wB[c].y; wr[6] = wB[c].z; wr[7] = wB[c].w;
#pragma unroll
                for (int bb = 0; bb < 8; bb++) {
                    const float ec = c == 0 ? e[bb].x : c == 1 ? e[bb].y
                                   : c == 2 ? e[bb].z : e[bb].w;
#pragma unroll
                    for (int rr = 0; rr < 8; rr++)
                        acc[rr][bb] = fmaf(wr[rr], ec, acc[rr][bb]);
                }
            }
        }
    } else {
        // r12 fallback: scattered 16B W reads
        const float* wp = W_ih + (size_t)row0 * EDIM;
        for (int t2 = 0; t2 < 75; t2++) {
            float4 w[8], e[8];
#pragma unroll
            for (int rr = 0; rr < 8; rr++)
                w[rr] = *(const float4*)(wp + rr * EDIM + 4 * t2);
#pragma unroll
            for (int bb = 0; bb < 8; bb++)
                e[bb] = *(const float4*)&embs[(bi * 8 + bb) * ESTR + 4 * t2];
#pragma unroll
            for (int rr = 0; rr < 8; rr++)
#pragma unroll
                for (int bb = 0; bb < 8; bb++) {
                    acc[rr][bb] = fmaf(w[rr].x, e[bb].x, acc[rr][bb]);
                    acc[rr][bb] = fmaf(w[rr].y, e[bb].y, acc[rr][bb]);
                    acc[rr][bb] = fmaf(w[rr].z, e[bb].z, acc[rr][bb]);
                    acc[rr][bb] = fmaf(w[rr].w, e[bb].w, acc[rr][bb]);
                }
        }
    }

    float* dstA = gates + (size_t)(s * GROUPS + 2 * bi)     * 8192 + row0 * 4;
    float* dstB = gates + (size_t)(s * GROUPS + 2 * bi + 1) * 8192 + row0 * 4;
#pragma unroll
    for (int rr = 0; rr < 8; rr++) {
        *(float4*)(dstA + 4 * rr) = make_float4(acc[rr][0], acc[rr][1], acc[rr][2], acc[rr][3]);
        *(float4*)(dstB + 4 * rr) = make_float4(acc[rr][4], acc[rr][5], acc[rr][6], acc[rr][7]);
    }
}

// ============================================================================
// Persistent LSTM — r12 VERBATIM (best measured: 1190 us).
// ============================================================================
extern "C" __global__ void __launch_bounds__(TPB, 2)
lstm_persist(const int* __restrict__ x, const float* __restrict__ emb,
             const float* __restrict__ W_ih, const float* __restrict__ W_hh,
             const float* __restrict__ b_ih, const float* __restrict__ b_hh,
             const float* __restrict__ gates,      // may be null
             unsigned long long* __restrict__ htag) // [2][16][2048] tagged h
{
    extern __shared__ float lds[];
    const int tid = threadIdx.x;
    const int g   = blockIdx.x & 15;
    const int j   = blockIdx.x >> 4;        // 0..31
    const bool pre = (gates != nullptr);

    const int rq = tid & 15;      // rows 4rq..4rq+3 (r = gate*16+u)
    const int kh = tid >> 4;      // k in [32kh, 32kh+32)
    const int wv = tid >> 6;      // wave 0..3
    const int ln = tid & 63;      // lane

    // ---- W_hh slice -> 128 VGPRs (static indexing only; rule #20) ----
    float4 w4[4][8];
#pragma unroll
    for (int p = 0; p < 4; p++) {
        const int r = 4 * rq + p;
        const size_t R = (size_t)((r >> 4) * HDIM + UNITS * j + (r & 15));
        const float* wp = W_hh + R * HDIM + 32 * kh;
#pragma unroll
        for (int kq = 0; kq < 8; kq++) w4[p][kq] = *(const float4*)(wp + 4 * kq);
    }
#pragma unroll
    for (int p = 0; p < 4; p++)
#pragma unroll
        for (int kq = 0; kq < 8; kq++)
            asm volatile("" : "+v"(w4[p][kq].x), "+v"(w4[p][kq].y),
                             "+v"(w4[p][kq].z), "+v"(w4[p][kq].w));

    // cell role: tid<64 owns (u = tid>>2, b = tid&3)
    const int uu = (tid & 63) >> 2;
    const int cb = tid & 3;
    float bias4[4];
#pragma unroll
    for (int gt = 0; gt < 4; gt++) {
        int R = gt * HDIM + UNITS * j + uu;
        bias4[gt] = b_ih[R] + b_hh[R];
    }
    float c_reg = 0.0f;

    const int swz = (kh & 3) << 2;      // pass-B read swizzle

    unsigned long long* const T0 = htag + (size_t)g * HT_GROUP;            // parity 0
    unsigned long long* const T1 = htag + HT_PAR + (size_t)g * HT_GROUP;   // parity 1

    __syncthreads();

    for (int s = 0; s < SEQL; s++) {
        const unsigned long long* Tin = (s & 1) ? T1 : T0;
        unsigned long long*       Tout = (s & 1) ? T0 : T1;

        // ---- (0) prefetch input-proj gates (non-temporal stream) ----
        float gp[4] = {0.f, 0.f, 0.f, 0.f};
        if (pre && tid < 64) {
            const float* gbase = gates + (size_t)(s * GROUPS + g) * 8192 + 64 * j;
#pragma unroll
            for (int gt = 0; gt < 4; gt++)
                gp[gt] = __builtin_nontemporal_load(gbase + gt * 2048 + tid);
        }

        float acc[4][4];
#pragma unroll
        for (int p = 0; p < 4; p++)
#pragma unroll
            for (int b = 0; b < 4; b++) acc[p][b] = 0.f;

        // ---- (1) fallback pass A (cold path; pre-path skips) ----
        if (!pre) {
            for (int i = tid; i < EDIM * GB; i += TPB) {
                int e = i >> 2, b = i & 3;
                int row = x[(GB * g + b) * SEQL + s];
                lds[EMB_OFF + i] = emb[(size_t)row * EDIM + e];
            }
            __syncthreads();
            if (kh < 15) {
                for (int e = 20 * kh; e < 20 * kh + 20; e++) {
                    float4 e0 = *(const float4*)&lds[EMB_OFF + 4 * e];
#pragma unroll
                    for (int p = 0; p < 4; p++) {
                        const int r = 4 * rq + p;
                        const size_t R = (size_t)((r >> 4) * HDIM + UNITS * j + (r & 15));
                        float wc = W_ih[R * EDIM + e];
                        acc[p][0] = fmaf(wc, e0.x, acc[p][0]);
                        acc[p][1] = fmaf(wc, e0.y, acc[p][1]);
                        acc[p][2] = fmaf(wc, e0.z, acc[p][2]);
                        acc[p][3] = fmaf(wc, e0.w, acc[p][3]);
                    }
                }
            }
            __syncthreads();
        }

        // ---- (2) WAVE-LOCAL poll+stage: rows k = 128*wv + {0,64} + ln ----
        {
            const unsigned tag = (unsigned)s;
#pragma unroll
            for (int rr = 0; rr < 2; rr++) {
                const int k = 128 * wv + 64 * rr + ln;
                const int vi = 4 * k;
                unsigned long long d0, d1, d2, d3;
                for (;;) {
                    d0 = __hip_atomic_load(Tin + vi + 0, __ATOMIC_RELAXED, __HIP_MEMORY_SCOPE_AGENT);
                    d1 = __hip_atomic_load(Tin + vi + 1, __ATOMIC_RELAXED, __HIP_MEMORY_SCOPE_AGENT);
                    d2 = __hip_atomic_load(Tin + vi + 2, __ATOMIC_RELAXED, __HIP_MEMORY_SCOPE_AGENT);
                    d3 = __hip_atomic_load(Tin + vi + 3, __ATOMIC_RELAXED, __HIP_MEMORY_SCOPE_AGENT);
                    if ((unsigned)(d0 >> 32) == tag && (unsigned)(d1 >> 32) == tag &&
                        (unsigned)(d2 >> 32) == tag && (unsigned)(d3 >> 32) == tag)
                        break;
                    __builtin_amdgcn_s_sleep(1);
                }
                const int phys = (4 * k) ^ (((k >> 5) & 3) << 2);
                float4 hv;
                hv.x = __uint_as_float((unsigned)d0);
                hv.y = __uint_as_float((unsigned)d1);
                hv.z = __uint_as_float((unsigned)d2);
                hv.w = __uint_as_float((unsigned)d3);
                *(float4*)&lds[phys] = hv;
            }
        }
        // wave-local RAW through LDS (in-order DS pipe); stop compiler reorder
        asm volatile("" ::: "memory");
        __builtin_amdgcn_sched_barrier(0);

        // ---- (3) pass B: W_hh regs x h LDS (conflict-free reads) ----
#pragma unroll
        for (int kq = 0; kq < 8; kq++) {
#pragma unroll
            for (int ki = 0; ki < 4; ki++) {
                const int kidx = 4 * kq + ki;
                const float4 h0 = *(const float4*)&lds[128 * kh + ((4 * kidx) ^ swz)];
#pragma unroll
                for (int p = 0; p < 4; p++) {
                    const float4 wvv = w4[p][kq];
                    const float wc = ki == 0 ? wvv.x : ki == 1 ? wvv.y
                                   : ki == 2 ? wvv.z : wvv.w;
                    acc[p][0] = fmaf(wc, h0.x, acc[p][0]);
                    acc[p][1] = fmaf(wc, h0.y, acc[p][1]);
                    acc[p][2] = fmaf(wc, h0.z, acc[p][2]);
                    acc[p][3] = fmaf(wc, h0.w, acc[p][3]);
                }
            }
        }

        // ---- (4) exchange k-partials: ex[r][b][kh] ----
#pragma unroll
        for (int p = 0; p < 4; p++) {
            const int base = EX_OFF + (4 * rq + p) * EX_RSTR + kh;
#pragma unroll
            for (int b = 0; b < 4; b++)
                lds[base + b * EX_BSTR] = acc[p][b];
        }
        __syncthreads();   // B1: all ex writes visible to cell readers

        // ---- (5) cell update + tagged store (tid<64 owns (u, b)) ----
        if (tid < 64) {
            float gs[4];
#pragma unroll
            for (int gt = 0; gt < 4; gt++) {
                float sum = bias4[gt] + gp[gt];
                const int base = EX_OFF + (gt * 16 + uu) * EX_RSTR + cb * EX_BSTR;
#pragma unroll
                for (int kk = 0; kk < 16; kk++) sum += lds[base + kk];
                gs[gt] = sum;
            }
            float iv = fast_sigmoid(gs[0]);
            float fv = fast_sigmoid(gs[1]);
            float gv = fast_tanh(gs[2]);
            float ov = fast_sigmoid(gs[3]);
            c_reg = fv * c_reg + iv * gv;
            float hv = ov * fast_tanh(c_reg);
            unsigned long long wword =
                ((unsigned long long)(unsigned)(s + 1) << 32) |
                (unsigned long long)__float_as_uint(hv);
            __hip_atomic_store(Tout + 64 * j + tid, wword,
                               __ATOMIC_RELAXED, __HIP_MEMORY_SCOPE_AGENT);
        }
        __syncthreads();   // B2: cell reads done before next step's ex writes
    }
}

// FC head + softmax. Final h: parity 0 (SEQL even); value = lo32.
extern "C" __global__ void __launch_bounds__(320)
lstm_epilogue(const unsigned long long* __restrict__ htag,
              const float* __restrict__ W_fc, const float* __restrict__ b_fc,
              float* __restrict__ out)
{
    __shared__ float sl[ODIM * BATCH];
    const int t = threadIdx.x;
    {
        int o = t / BATCH, b = t - o * BATCH;
        const unsigned long long* hb = htag + (size_t)(b >> 2) * HT_GROUP;
        const int bc = b & 3;
        float acc = b_fc[o];
        const float4* wv = (const float4*)(W_fc + o * HDIM);
#pragma unroll 8
        for (int k4 = 0; k4 < HDIM / 4; k4++) {
            float4 w = wv[k4];
            const int k0 = 4 * k4;
            acc = fmaf(__uint_as_float((unsigned)hb[(k0 + 0) * 4 + bc]), w.x, acc);
            acc = fmaf(__uint_as_float((unsigned)hb[(k0 + 1) * 4 + bc]), w.y, acc);
            acc = fmaf(__uint_as_float((unsigned)hb[(k0 + 2) * 4 + bc]), w.z, acc);
            acc = fmaf(__uint_as_float((unsigned)hb[(k0 + 3) * 4 + bc]), w.w, acc);
        }
        sl[o * BATCH + b] = acc;
    }
    __syncthreads();
    if (t < BATCH) {
        float l0 = sl[t], l1 = sl[BATCH + t], l2 = sl[2 * BATCH + t];
        float l3 = sl[3 * BATCH + t], l4 = sl[4 * BATCH + t];
        float m = fmaxf(fmaxf(fmaxf(l0, l1), fmaxf(l2, l3)), l4);
        float e0 = __expf(l0 - m), e1 = __expf(l1 - m), e2 = __expf(l2 - m);
        float e3 = __expf(l3 - m), e4 = __expf(l4 - m);
        float inv = 1.0f / (e0 + e1 + e2 + e3 + e4);
        out[t * ODIM + 0] = e0 * inv;
        out[t * ODIM + 1] = e1 * inv;
        out[t * ODIM + 2] = e2 * inv;
        out[t * ODIM + 3] = e3 * inv;
        out[t * ODIM + 4] = e4 * inv;
    }
}

extern "C" void kernel_launch(void* const* d_in, const int* in_sizes, int n_in,
                              void* d_out, int out_size, void* d_ws, size_t ws_size,
                              hipStream_t stream)
{
    const int*   x    = (const int*)d_in[0];
    const float* emb  = (const float*)d_in[1];
    const float* W_ih = (const float*)d_in[2];
    const float* W_hh = (const float*)d_in[3];
    const float* b_ih = (const float*)d_in[4];
    const float* b_hh = (const float*)d_in[5];
    const float* W_fc = (const float*)d_in[6];
    const float* b_fc = (const float*)d_in[7];
    float* out = (float*)d_out;

    // ws layout: [htag 512 KiB][gates 104.9 MB (optional)][W_ihT 2.4 MB (optional)]
    unsigned long long* htag = (unsigned long long*)d_ws;
    const size_t gates_bytes = GATES_FLOATS * sizeof(float);
    const size_t wt_bytes    = WT_FLOATS * sizeof(float);
    float* gates = nullptr;
    float* wT    = nullptr;
    if (ws_size >= (size_t)HT_BYTES + gates_bytes) {
        gates = (float*)((char*)d_ws + HT_BYTES);
        if (ws_size >= (size_t)HT_BYTES + gates_bytes + wt_bytes)
            wT = (float*)((char*)d_ws + HT_BYTES + gates_bytes);
    }

    (void)hipMemsetAsync(htag, 0, HT_BYTES, stream);   // tag 0 / h = 0 for step 0

    (void)hipFuncSetAttribute((const void*)lstm_persist,
                              hipFuncAttributeMaxDynamicSharedMemorySize, LDS_BYTES);
    if (gates) {
        (void)hipFuncSetAttribute((const void*)lstm_pre,
                                  hipFuncAttributeMaxDynamicSharedMemorySize, PRE_LDS_BYTES);
        if (wT) {
            dim3 tg(NROW / 32, (EDIM + 31) / 32);
            wih_transpose<<<tg, 256, 0, stream>>>(W_ih, wT);
        }
        lstm_pre<<<SEQL * 8, 256, PRE_LDS_BYTES, stream>>>(x, emb, W_ih, wT, gates);
    }

    lstm_persist<<<NWG, TPB, LDS_BYTES, stream>>>(x, emb, W_ih, W_hh, b_ih, b_hh,
                                                  gates, htag);

    lstm_epilogue<<<1, 320, 0, stream>>>(htag, W_fc, b_fc, out);
}